// Round 2
// baseline (2194.330 us; speedup 1.0000x reference)
//
#include <hip/hip_runtime.h>

typedef unsigned short u16;
typedef short short8 __attribute__((ext_vector_type(8)));
typedef float f32x4 __attribute__((ext_vector_type(4)));

struct __attribute__((aligned(8), may_alias)) U2 { unsigned int x, y; };
struct __attribute__((aligned(16), may_alias)) U4 { unsigned int x, y, z, w; };
struct __attribute__((aligned(16), may_alias)) F4 { float x, y, z, w; };

__device__ __forceinline__ float bf2f(u16 h) {
    union { unsigned int u; float f; } x; x.u = ((unsigned int)h) << 16; return x.f;
}
__device__ __forceinline__ u16 f2bf(float f) {
    union { float f; unsigned int u; } x; x.f = f;
    return (u16)((x.u + 0x7FFFu + ((x.u >> 16) & 1u)) >> 16);
}
__device__ __forceinline__ short8 lds8(const u16* p) {
    union { U2 q[2]; short8 s; } u;
    u.q[0] = *(const U2*)p;
    u.q[1] = *(const U2*)(p + 4);
    return u.s;
}

// ---------------------------------------------------------------------------
// Transpose 5 fp32 weight matrices (2048x2048) into bf16: Wt[n][k] = bf16(W[k][n])
// ---------------------------------------------------------------------------
__global__ void transpose5(const float* __restrict__ s0, const float* __restrict__ s1,
                           const float* __restrict__ s2, const float* __restrict__ s3,
                           const float* __restrict__ s4,
                           u16* __restrict__ d0, u16* __restrict__ d1,
                           u16* __restrict__ d2, u16* __restrict__ d3,
                           u16* __restrict__ d4)
{
    const float* S; u16* D;
    switch (blockIdx.z) {
        case 0: S = s0; D = d0; break;
        case 1: S = s1; D = d1; break;
        case 2: S = s2; D = d2; break;
        case 3: S = s3; D = d3; break;
        default: S = s4; D = d4; break;
    }
    __shared__ float tile[32][33];
    int tx = threadIdx.x, ty = threadIdx.y;
    int bx = blockIdx.x * 32, by = blockIdx.y * 32;
    #pragma unroll
    for (int i = 0; i < 32; i += 8)
        tile[ty + i][tx] = S[(size_t)(by + ty + i) * 2048 + bx + tx];
    __syncthreads();
    #pragma unroll
    for (int i = 0; i < 32; i += 8)
        D[(size_t)(bx + ty + i) * 2048 + by + tx] = f2bf(tile[tx][ty + i]);
}

// ---------------------------------------------------------------------------
// Projection GEMM: C_bf16[M,N] = mix(A_f32)[M,K] @ Bt_bf16[N,K]^T, fp32 accum.
// Token-shift mix fused into A staging:
//   a[t][c] = x_prev[c] + tmix[c]*(x[t][c]-x_prev[c]),  x_prev=0 at t%4096==0
// ---------------------------------------------------------------------------
__global__ __launch_bounds__(256, 1) void gemm_proj(
    const float* __restrict__ A, const u16* __restrict__ Bt, u16* __restrict__ C,
    int M, int N, int K, const float* __restrict__ tmix)
{
    __shared__ u16 As[128][36];
    __shared__ u16 Bs[128][36];
    const int tid = threadIdx.x;
    const int lane = tid & 63, wv = tid >> 6;
    const int quad = lane >> 4, l16 = lane & 15;
    const int wm = (wv >> 1) * 64, wn = (wv & 1) * 64;
    const int bm = blockIdx.x * 128, bn = blockIdx.y * 128;

    f32x4 acc[4][4];
    const f32x4 zero4 = {0.f, 0.f, 0.f, 0.f};
    #pragma unroll
    for (int i = 0; i < 4; ++i)
        #pragma unroll
        for (int j = 0; j < 4; ++j) acc[i][j] = zero4;

    for (int k0 = 0; k0 < K; k0 += 32) {
        __syncthreads();
        #pragma unroll
        for (int it = 0; it < 2; ++it) {
            int c16 = it * 256 + tid;
            int row = c16 >> 2, seg = c16 & 3;
            // ---- A tile: fp32 load + mix + round to bf16 ----
            {
                const float* ap = A + (size_t)(bm + row) * K + k0 + seg * 8;
                const float* tp = tmix + k0 + seg * 8;
                bool first = ((bm + row) & 4095) == 0;
                F4 xlo = *(const F4*)ap, xhi = *(const F4*)(ap + 4);
                F4 tlo = *(const F4*)tp, thi = *(const F4*)(tp + 4);
                F4 plo = {0.f, 0.f, 0.f, 0.f}, phi = {0.f, 0.f, 0.f, 0.f};
                if (!first) { plo = *(const F4*)(ap - K); phi = *(const F4*)(ap - K + 4); }
                float xc[8] = {xlo.x, xlo.y, xlo.z, xlo.w, xhi.x, xhi.y, xhi.z, xhi.w};
                float xp[8] = {plo.x, plo.y, plo.z, plo.w, phi.x, phi.y, phi.z, phi.w};
                float tm[8] = {tlo.x, tlo.y, tlo.z, tlo.w, thi.x, thi.y, thi.z, thi.w};
                union { u16 s[8]; U2 q[2]; } ov;
                #pragma unroll
                for (int e = 0; e < 8; ++e)
                    ov.s[e] = f2bf(xp[e] + tm[e] * (xc[e] - xp[e]));
                u16* d = &As[row][seg * 8];
                *(U2*)d = ov.q[0];
                *(U2*)(d + 4) = ov.q[1];
            }
            // ---- B tile (already bf16, transposed) ----
            {
                const u16* bp = Bt + (size_t)(bn + row) * K + k0 + seg * 8;
                union { U4 v; U2 q[2]; } w2; w2.v = *(const U4*)bp;
                u16* d = &Bs[row][seg * 8];
                *(U2*)d = w2.q[0];
                *(U2*)(d + 4) = w2.q[1];
            }
        }
        __syncthreads();
        short8 af[4], bfv[4];
        #pragma unroll
        for (int mt = 0; mt < 4; ++mt) af[mt] = lds8(&As[wm + mt * 16 + l16][quad * 8]);
        #pragma unroll
        for (int nt = 0; nt < 4; ++nt) bfv[nt] = lds8(&Bs[wn + nt * 16 + l16][quad * 8]);
        #pragma unroll
        for (int mt = 0; mt < 4; ++mt)
            #pragma unroll
            for (int nt = 0; nt < 4; ++nt)
                acc[mt][nt] = __builtin_amdgcn_mfma_f32_16x16x32_bf16(
                    af[mt], bfv[nt], acc[mt][nt], 0, 0, 0);
    }
    #pragma unroll
    for (int mt = 0; mt < 4; ++mt)
        #pragma unroll
        for (int nt = 0; nt < 4; ++nt)
            #pragma unroll
            for (int r = 0; r < 4; ++r) {
                int row = bm + wm + mt * 16 + quad * 4 + r;
                int col = bn + wn + nt * 16 + l16;
                C[(size_t)row * N + col] = f2bf(acc[mt][nt][r]);
            }
}

// ---------------------------------------------------------------------------
// Output GEMM: C_f32[M,N] = A_bf16[M,K] @ Bt_bf16[N,K]^T, fp32 accum.
// ---------------------------------------------------------------------------
__global__ __launch_bounds__(256, 1) void gemm_obt(
    const u16* __restrict__ A, const u16* __restrict__ Bt, float* __restrict__ C,
    int M, int N, int K)
{
    __shared__ u16 As[128][36];
    __shared__ u16 Bs[128][36];
    const int tid = threadIdx.x;
    const int lane = tid & 63, wv = tid >> 6;
    const int quad = lane >> 4, l16 = lane & 15;
    const int wm = (wv >> 1) * 64, wn = (wv & 1) * 64;
    const int bm = blockIdx.x * 128, bn = blockIdx.y * 128;

    f32x4 acc[4][4];
    const f32x4 zero4 = {0.f, 0.f, 0.f, 0.f};
    #pragma unroll
    for (int i = 0; i < 4; ++i)
        #pragma unroll
        for (int j = 0; j < 4; ++j) acc[i][j] = zero4;

    for (int k0 = 0; k0 < K; k0 += 32) {
        __syncthreads();
        #pragma unroll
        for (int it = 0; it < 2; ++it) {
            int c16 = it * 256 + tid;
            int row = c16 >> 2, seg = c16 & 3;
            {
                const u16* ap = A + (size_t)(bm + row) * K + k0 + seg * 8;
                union { U4 v; U2 q[2]; } w2; w2.v = *(const U4*)ap;
                u16* d = &As[row][seg * 8];
                *(U2*)d = w2.q[0];
                *(U2*)(d + 4) = w2.q[1];
            }
            {
                const u16* bp = Bt + (size_t)(bn + row) * K + k0 + seg * 8;
                union { U4 v; U2 q[2]; } w2; w2.v = *(const U4*)bp;
                u16* d = &Bs[row][seg * 8];
                *(U2*)d = w2.q[0];
                *(U2*)(d + 4) = w2.q[1];
            }
        }
        __syncthreads();
        short8 af[4], bfv[4];
        #pragma unroll
        for (int mt = 0; mt < 4; ++mt) af[mt] = lds8(&As[wm + mt * 16 + l16][quad * 8]);
        #pragma unroll
        for (int nt = 0; nt < 4; ++nt) bfv[nt] = lds8(&Bs[wn + nt * 16 + l16][quad * 8]);
        #pragma unroll
        for (int mt = 0; mt < 4; ++mt)
            #pragma unroll
            for (int nt = 0; nt < 4; ++nt)
                acc[mt][nt] = __builtin_amdgcn_mfma_f32_16x16x32_bf16(
                    af[mt], bfv[nt], acc[mt][nt], 0, 0, 0);
    }
    #pragma unroll
    for (int mt = 0; mt < 4; ++mt)
        #pragma unroll
        for (int nt = 0; nt < 4; ++nt)
            #pragma unroll
            for (int r = 0; r < 4; ++r) {
                int row = bm + wm + mt * 16 + quad * 4 + r;
                int col = bn + wn + nt * 16 + l16;
                C[(size_t)row * N + col] = acc[mt][nt][r];
            }
}

// ---------------------------------------------------------------------------
// WKV chunked scan + fused groupnorm/silu-gate epilogue.
// One block per (b,h); 8 waves; wave I owns row-tile I (64 rows of the chunk).
// State master lives in registers (fp32): wave w owns tiles (w>>1, {(w&1)*2, +1}).
// r/k/v/g buffers are bf16; td/tf/gamma/beta/st0 are fp32; Xout is bf16.
// ---------------------------------------------------------------------------
__global__ __launch_bounds__(512, 1) void wkv_kernel(
    const u16* __restrict__ Rb, const u16* __restrict__ Kb,
    const u16* __restrict__ Vb, const u16* __restrict__ Gb,
    const float* __restrict__ td, const float* __restrict__ tf,
    const float* __restrict__ gamma, const float* __restrict__ beta,
    const float* __restrict__ st0, u16* __restrict__ Xout)
{
    __shared__ u16 kt[64][72];     // k tile [t_local][s]
    __shared__ u16 vtT[64][72];    // v tile transposed [s][t_local]
    __shared__ u16 Pb[8][64][40];  // per-wave P scratch (32-col halves); also aliases stT
    __shared__ float wpow[513];    // w1^p
    u16* stT = &Pb[0][0][0];       // [64][72] view: stT[s2*72 + s1] = state[s1][s2]

    const int blk = blockIdx.x;
    const int b = blk >> 5, h = blk & 31;
    const int tid = threadIdx.x;
    const int w = tid >> 6, lane = tid & 63;
    const int quad = lane >> 4, l16 = lane & 15;

    const float E = expf(td[h]);   // ln(1/w1)
    const float u = tf[h];
    for (int p = tid; p <= 512; p += 512) wpow[p] = expf(-(float)p * E);

    // state registers
    const int mtS = w >> 1;
    const int ntS0 = (w & 1) * 2;
    f32x4 stReg[2];
    {
        const float* sp = st0 + (((size_t)b * 32 + h) << 12);
        #pragma unroll
        for (int q = 0; q < 2; ++q)
            #pragma unroll
            for (int r = 0; r < 4; ++r) {
                int s1 = mtS * 16 + quad * 4 + r;
                int s2 = (ntS0 + q) * 16 + l16;
                stReg[q][r] = sp[s1 * 64 + s2];
            }
    }

    const size_t rowbase = ((size_t)b * 4096) * 2048 + (size_t)h * 64;
    const f32x4 zero4 = {0.f, 0.f, 0.f, 0.f};
    __syncthreads();  // wpow ready

    for (int c = 0; c < 8; ++c) {
        const int t0 = c * 512;
        __syncthreads();  // guard Pb/kt/vtT reuse from prior chunk
        // ---- broadcast state to LDS (bf16, transposed) ----
        #pragma unroll
        for (int q = 0; q < 2; ++q)
            #pragma unroll
            for (int r = 0; r < 4; ++r) {
                int s1 = mtS * 16 + quad * 4 + r;
                int s2 = (ntS0 + q) * 16 + l16;
                stT[s2 * 72 + s1] = f2bf(stReg[q][r]);
            }
        __syncthreads();

        // ---- load r fragments for this wave's 64 rows ----
        short8 ar[4][2];
        #pragma unroll
        for (int mt = 0; mt < 4; ++mt)
            #pragma unroll
            for (int ks = 0; ks < 2; ++ks) {
                int t = t0 + w * 64 + mt * 16 + l16;
                const u16* p = Rb + rowbase + (size_t)t * 2048 + ks * 32 + quad * 8;
                union { U4 v; short8 s; } uu; uu.v = *(const U4*)p;
                ar[mt][ks] = uu.s;
            }

        // ---- phase 1: acc = (r @ state) * w1^i ----
        f32x4 acc[4][4];
        #pragma unroll
        for (int i = 0; i < 4; ++i)
            #pragma unroll
            for (int j = 0; j < 4; ++j) acc[i][j] = zero4;
        #pragma unroll
        for (int ks = 0; ks < 2; ++ks)
            #pragma unroll
            for (int nt = 0; nt < 4; ++nt) {
                short8 bs = lds8(&stT[(nt * 16 + l16) * 72 + ks * 32 + quad * 8]);
                #pragma unroll
                for (int mt = 0; mt < 4; ++mt)
                    acc[mt][nt] = __builtin_amdgcn_mfma_f32_16x16x32_bf16(
                        ar[mt][ks], bs, acc[mt][nt], 0, 0, 0);
            }
        #pragma unroll
        for (int mt = 0; mt < 4; ++mt)
            #pragma unroll
            for (int r = 0; r < 4; ++r) {
                float f = wpow[w * 64 + mt * 16 + quad * 4 + r];
                #pragma unroll
                for (int nt = 0; nt < 4; ++nt) acc[mt][nt][r] *= f;
            }

        f32x4 sacc[2] = {zero4, zero4};

        // ---- phase 2: J-tile loop (attention + state partials) ----
        for (int J = 0; J < 8; ++J) {
            __syncthreads();
            {   // stage kt, vtT
                int row = tid >> 3, seg = tid & 7;
                size_t goff = rowbase + (size_t)(t0 + J * 64 + row) * 2048 + seg * 8;
                union { U4 v; u16 s[8]; } kv, vv;
                kv.v = *(const U4*)(Kb + goff);
                vv.v = *(const U4*)(Vb + goff);
                *(U4*)&kt[row][seg * 8] = kv.v;
                #pragma unroll
                for (int e = 0; e < 8; ++e) vtT[seg * 8 + e][row] = vv.s[e];
            }
            __syncthreads();
            if (w >= J) {
                #pragma unroll
                for (int half = 0; half < 2; ++half) {
                    #pragma unroll
                    for (int jt2 = 0; jt2 < 2; ++jt2) {
                        int jt = half * 2 + jt2;
                        short8 bk0 = lds8(&kt[jt * 16 + l16][quad * 8]);
                        short8 bk1 = lds8(&kt[jt * 16 + l16][32 + quad * 8]);
                        #pragma unroll
                        for (int mt = 0; mt < 4; ++mt) {
                            f32x4 s4 = zero4;
                            s4 = __builtin_amdgcn_mfma_f32_16x16x32_bf16(ar[mt][0], bk0, s4, 0, 0, 0);
                            s4 = __builtin_amdgcn_mfma_f32_16x16x32_bf16(ar[mt][1], bk1, s4, 0, 0, 0);
                            int ibase = w * 64 + mt * 16 + quad * 4;
                            int j = J * 64 + jt * 16 + l16;
                            #pragma unroll
                            for (int r = 0; r < 4; ++r) {
                                int i = ibase + r;
                                float f = (j < i) ? wpow[i - j - 1] : ((j == i) ? u : 0.f);
                                Pb[w][mt * 16 + quad * 4 + r][jt2 * 16 + l16] = f2bf(s4[r] * f);
                            }
                        }
                    }
                    __builtin_amdgcn_wave_barrier();
                    short8 ap[4];
                    #pragma unroll
                    for (int mt = 0; mt < 4; ++mt)
                        ap[mt] = lds8(&Pb[w][mt * 16 + l16][quad * 8]);
                    #pragma unroll
                    for (int nt = 0; nt < 4; ++nt) {
                        short8 bv = lds8(&vtT[nt * 16 + l16][half * 32 + quad * 8]);
                        #pragma unroll
                        for (int mt = 0; mt < 4; ++mt)
                            acc[mt][nt] = __builtin_amdgcn_mfma_f32_16x16x32_bf16(
                                ap[mt], bv, acc[mt][nt], 0, 0, 0);
                    }
                }
            }
            // state partial: s_part += (k * w1^(511-t))^T @ v  for this J tile
            {
                short8 aS[2];
                #pragma unroll
                for (int ks = 0; ks < 2; ++ks) {
                    union { short8 s; u16 us[8]; } t8;
                    #pragma unroll
                    for (int jj = 0; jj < 8; ++jj) {
                        int tl = ks * 32 + quad * 8 + jj;
                        float f = bf2f(kt[tl][mtS * 16 + l16]) * wpow[511 - (J * 64 + tl)];
                        t8.us[jj] = f2bf(f);
                    }
                    aS[ks] = t8.s;
                }
                #pragma unroll
                for (int q = 0; q < 2; ++q) {
                    short8 bv0 = lds8(&vtT[(ntS0 + q) * 16 + l16][quad * 8]);
                    short8 bv1 = lds8(&vtT[(ntS0 + q) * 16 + l16][32 + quad * 8]);
                    sacc[q] = __builtin_amdgcn_mfma_f32_16x16x32_bf16(aS[0], bv0, sacc[q], 0, 0, 0);
                    sacc[q] = __builtin_amdgcn_mfma_f32_16x16x32_bf16(aS[1], bv1, sacc[q], 0, 0, 0);
                }
            }
        }

        // ---- state update (registers only) ----
        {
            float wsT = wpow[512];
            #pragma unroll
            for (int q = 0; q < 2; ++q)
                #pragma unroll
                for (int r = 0; r < 4; ++r)
                    stReg[q][r] = wsT * stReg[q][r] + sacc[q][r];
        }

        // ---- epilogue: groupnorm(out/8)*gamma+beta, * silu(g), write bf16 ----
        #pragma unroll
        for (int mt = 0; mt < 4; ++mt) {
            float rsum[4], rsq[4];
            #pragma unroll
            for (int r = 0; r < 4; ++r) {
                float s = 0.f, sq = 0.f;
                #pragma unroll
                for (int nt = 0; nt < 4; ++nt) {
                    float v = acc[mt][nt][r];
                    s += v; sq += v * v;
                }
                rsum[r] = s; rsq[r] = sq;
            }
            #pragma unroll
            for (int off = 1; off < 16; off <<= 1)
                #pragma unroll
                for (int r = 0; r < 4; ++r) {
                    rsum[r] += __shfl_xor(rsum[r], off);
                    rsq[r] += __shfl_xor(rsq[r], off);
                }
            #pragma unroll
            for (int r = 0; r < 4; ++r) {
                float mean = rsum[r] * (1.f / 512.f);   // mean of acc/8 over 64 ch
                float var = rsq[r] * (1.f / 4096.f) - mean * mean;
                float rstd = rsqrtf(var + 1e-5f);
                int tg = t0 + w * 64 + mt * 16 + quad * 4 + r;
                size_t obase = rowbase + (size_t)tg * 2048;
                #pragma unroll
                for (int nt = 0; nt < 4; ++nt) {
                    int ch = nt * 16 + l16;
                    float y = acc[mt][nt][r] * 0.125f;
                    float xn = (y - mean) * rstd * gamma[h * 64 + ch] + beta[h * 64 + ch];
                    float gl = bf2f(Gb[obase + ch]);
                    float sg = gl / (1.f + expf(-gl));
                    Xout[obase + ch] = f2bf(xn * sg);
                }
            }
        }
    }
}

// ---------------------------------------------------------------------------
extern "C" void kernel_launch(void* const* d_in, const int* in_sizes, int n_in,
                              void* d_out, int out_size, void* d_ws, size_t ws_size,
                              hipStream_t stream)
{
    const float* x   = (const float*)d_in[0];
    const float* Wr  = (const float*)d_in[1];
    const float* Wk  = (const float*)d_in[2];
    const float* Wv  = (const float*)d_in[3];
    const float* Wg  = (const float*)d_in[4];
    const float* Wo  = (const float*)d_in[5];
    const float* gam = (const float*)d_in[6];
    const float* bet = (const float*)d_in[7];
    const float* tmk = (const float*)d_in[8];
    const float* tmv = (const float*)d_in[9];
    const float* tmr = (const float*)d_in[10];
    const float* tmg = (const float*)d_in[11];
    const float* td  = (const float*)d_in[12];
    const float* tf  = (const float*)d_in[13];
    const float* st0 = (const float*)d_in[14];
    float* out = (float*)d_out;

    char* ws = (char*)d_ws;
    const size_t WSZ = (size_t)2048 * 2048 * 2;   // 8 MiB per transposed bf16 weight
    const size_t ASZ = (size_t)16384 * 2048 * 2;  // 64 MiB per bf16 activation
    u16* WtR = (u16*)(ws + 0 * WSZ);
    u16* WtK = (u16*)(ws + 1 * WSZ);
    u16* WtV = (u16*)(ws + 2 * WSZ);
    u16* WtG = (u16*)(ws + 3 * WSZ);
    u16* WtO = (u16*)(ws + 4 * WSZ);
    char* act = ws + 5 * WSZ;
    u16* rb = (u16*)(act + 0 * ASZ);
    u16* kb = (u16*)(act + 1 * ASZ);
    u16* vb = (u16*)(act + 2 * ASZ);
    u16* gb = (u16*)(act + 3 * ASZ);
    u16* xo = gb;  // alias: wkv epilogue reads Gb[addr] strictly before writing Xout[addr]

    transpose5<<<dim3(64, 64, 5), dim3(32, 8), 0, stream>>>(
        Wr, Wk, Wv, Wg, Wo, WtR, WtK, WtV, WtG, WtO);

    dim3 ggrid(128, 16), gblk(256);
    gemm_proj<<<ggrid, gblk, 0, stream>>>(x, WtR, rb, 16384, 2048, 2048, tmr);
    gemm_proj<<<ggrid, gblk, 0, stream>>>(x, WtK, kb, 16384, 2048, 2048, tmk);
    gemm_proj<<<ggrid, gblk, 0, stream>>>(x, WtV, vb, 16384, 2048, 2048, tmv);
    gemm_proj<<<ggrid, gblk, 0, stream>>>(x, WtG, gb, 16384, 2048, 2048, tmg);

    wkv_kernel<<<dim3(128), dim3(512), 0, stream>>>(
        rb, kb, vb, gb, td, tf, gam, bet, st0, xo);

    gemm_obt<<<ggrid, gblk, 0, stream>>>(xo, WtO, out, 16384, 2048, 2048);
}